// Round 1
// baseline (405.003 us; speedup 1.0000x reference)
//
#include <hip/hip_runtime.h>
#include <hip/hip_bf16.h>

// SFM model: B=256, T=128, D=128, FREQ=16, HID=128
// Phase 1: P[(b*128+t)*528 + c] = x(b,t,:) @ [W_i|W_ste|W_c|W_o|W_fre] + bias
//          (col layout: 0-127 i, 128-255 ste, 256-383 c, 384-511 o, 512-527 fre)
// Phase 2: sequential scan, 1 block per batch element, U columns in VGPRs,
//          h broadcast via readlane, trig via 16-entry period tables.

__device__ __forceinline__ float hsig_f(float z) {
    return fminf(fmaxf(z * (1.0f / 6.0f) + 0.5f, 0.0f), 1.0f);
}

// ---------------- Phase 1: projection GEMM ----------------
__global__ __launch_bounds__(256) void proj_gemm(
    const float* __restrict__ input,
    const float* __restrict__ Wi, const float* __restrict__ Wste,
    const float* __restrict__ Wc, const float* __restrict__ Wo,
    const float* __restrict__ Wfre,
    const float* __restrict__ bi, const float* __restrict__ bste,
    const float* __restrict__ bc, const float* __restrict__ bo,
    const float* __restrict__ bfre,
    float* __restrict__ P)
{
    __shared__ __align__(16) float XT[128 * 64];  // [d][rr]
    __shared__ __align__(16) float WT[128 * 64];  // [d][cc]

    const int ct = blockIdx.y;  // 0..8
    const float* W; const float* bias; int ncols, ccol0, cbase;
    if (ct < 2)      { W = Wi;   bias = bi;   ncols = 128; ccol0 = (ct & 1) * 64; cbase = ct * 64; }
    else if (ct < 4) { W = Wste; bias = bste; ncols = 128; ccol0 = (ct & 1) * 64; cbase = ct * 64; }
    else if (ct < 6) { W = Wc;   bias = bc;   ncols = 128; ccol0 = (ct & 1) * 64; cbase = ct * 64; }
    else if (ct < 8) { W = Wo;   bias = bo;   ncols = 128; ccol0 = (ct & 1) * 64; cbase = ct * 64; }
    else             { W = Wfre; bias = bfre; ncols = 16;  ccol0 = 0;             cbase = 512; }

    const int R  = blockIdx.x * 64;      // global row tile (rows = b*128 + t)
    const int b  = R >> 7;
    const int t0 = R & 127;
    const int tid = threadIdx.x;

    // X tile: rows R..R+63, all 128 d.  x[b,t,d] = input[b*16384 + d*128 + t]
    const float* xbase = input + (size_t)b * 16384 + t0;
#pragma unroll
    for (int i = 0; i < 8; i++) {
        int flat4 = (i * 256 + tid) * 4;
        int rr = flat4 & 63, d = flat4 >> 6;
        float4 v = *(const float4*)(xbase + d * 128 + rr);
        *(float4*)(&XT[d * 64 + rr]) = v;
    }
    // W tile: [d][cc], zero-padded past ncols
#pragma unroll
    for (int i = 0; i < 8; i++) {
        int flat4 = (i * 256 + tid) * 4;
        int cc = flat4 & 63, d = flat4 >> 6;
        float4 v = make_float4(0.f, 0.f, 0.f, 0.f);
        if (cc < ncols) v = *(const float4*)(W + d * ncols + ccol0 + cc);
        *(float4*)(&WT[d * 64 + cc]) = v;
    }
    __syncthreads();

    const int tx = tid & 15, ty = tid >> 4;
    float acc[4][4] = {};
#pragma unroll 4
    for (int k = 0; k < 128; k++) {
        float4 xa = *(const float4*)(&XT[k * 64 + ty * 4]);
        float4 wb = *(const float4*)(&WT[k * 64 + tx * 4]);
        acc[0][0] = fmaf(xa.x, wb.x, acc[0][0]); acc[0][1] = fmaf(xa.x, wb.y, acc[0][1]);
        acc[0][2] = fmaf(xa.x, wb.z, acc[0][2]); acc[0][3] = fmaf(xa.x, wb.w, acc[0][3]);
        acc[1][0] = fmaf(xa.y, wb.x, acc[1][0]); acc[1][1] = fmaf(xa.y, wb.y, acc[1][1]);
        acc[1][2] = fmaf(xa.y, wb.z, acc[1][2]); acc[1][3] = fmaf(xa.y, wb.w, acc[1][3]);
        acc[2][0] = fmaf(xa.z, wb.x, acc[2][0]); acc[2][1] = fmaf(xa.z, wb.y, acc[2][1]);
        acc[2][2] = fmaf(xa.z, wb.z, acc[2][2]); acc[2][3] = fmaf(xa.z, wb.w, acc[2][3]);
        acc[3][0] = fmaf(xa.w, wb.x, acc[3][0]); acc[3][1] = fmaf(xa.w, wb.y, acc[3][1]);
        acc[3][2] = fmaf(xa.w, wb.z, acc[3][2]); acc[3][3] = fmaf(xa.w, wb.w, acc[3][3]);
    }

    const int colv = tx * 4;
    const bool valid = (ct < 8) || (colv < 16);
    if (valid) {
        float4 b4;
        b4.x = bias[ccol0 + colv + 0]; b4.y = bias[ccol0 + colv + 1];
        b4.z = bias[ccol0 + colv + 2]; b4.w = bias[ccol0 + colv + 3];
#pragma unroll
        for (int jr = 0; jr < 4; jr++) {
            int row = R + ty * 4 + jr;
            float4 o;
            o.x = acc[jr][0] + b4.x; o.y = acc[jr][1] + b4.y;
            o.z = acc[jr][2] + b4.z; o.w = acc[jr][3] + b4.w;
            *(float4*)(&P[(size_t)row * 528 + cbase + colv]) = o;
        }
    }
}

// ---------------- Phase 2: sequential recurrence ----------------
__global__ __launch_bounds__(512, 2) void recur_kernel(
    const float* __restrict__ P,
    const float* __restrict__ Ui, const float* __restrict__ Uste,
    const float* __restrict__ Uc, const float* __restrict__ Uo,
    const float* __restrict__ Ufre,
    const float* __restrict__ Ua, const float* __restrict__ ba_g,
    const float* __restrict__ Wsym, const float* __restrict__ bsym,
    float* __restrict__ out)
{
    __shared__ float ufre_lds[128 * 17];  // padded stride 17 -> conflict-free column reads
    __shared__ float costab[16], sintab[16];
    __shared__ float gate_buf[512];       // [i|ste|c|o] x 128
    __shared__ float fre_buf[16];
    __shared__ float h_buf[128];

    const int tid  = threadIdx.x;
    const int lane = tid & 63;
    const int wv   = tid >> 6;    // wave 0..7
    const int m    = tid >> 7;    // matrix 0..3 (i,ste,c,o)
    const int j    = tid & 127;   // output column
    const int hh   = tid >> 2;    // state: h index 0..127
    const int f0   = (tid & 3) * 4;  // state: first of 4 freq slots
    const int b    = blockIdx.x;

    // LDS init
    for (int e = tid; e < 2048; e += 512)
        ufre_lds[(e >> 4) * 17 + (e & 15)] = Ufre[e];
    if (tid < 16) {
        float ang = 6.283185307179586f * (float)tid * (1.0f / 16.0f);
        costab[tid] = cosf(ang);
        sintab[tid] = sinf(ang);
    }

    // U column -> registers (coalesced: consecutive lanes = consecutive cols)
    const float* Uptr = (m == 0) ? Ui : (m == 1) ? Uste : (m == 2) ? Uc : Uo;
    float Ucol[128];
#pragma unroll
    for (int k = 0; k < 128; k++) Ucol[k] = Uptr[k * 128 + j];

    float ua4[4];
#pragma unroll
    for (int q = 0; q < 4; q++) ua4[q] = Ua[f0 + q];
    const float ba = ba_g[hh];

    float hA = 0.0f, hB = 0.0f;  // h[lane], h[64+lane] (wave-replicated)
    float Sre0 = 0.f, Sre1 = 0.f, Sre2 = 0.f, Sre3 = 0.f;
    float Sim0 = 0.f, Sim1 = 0.f, Sim2 = 0.f, Sim3 = 0.f;
    int idx0 = 0, idx1 = 0, idx2 = 0, idx3 = 0;  // (t*f) & 15 accumulators

    __syncthreads();

    const float* pr = P + (size_t)b * 128 * 528;
    for (int t = 0; t < 128; t++) {
        const float xpre  = pr[tid];
        const float xfrev = pr[512 + 2 * wv + (lane & 1)];

        // ---- main matvec: out[j] = sum_k h[k] * U[k][j] ----
        float acc0 = 0.f, acc1 = 0.f;
#pragma unroll
        for (int kk = 0; kk < 64; kk++) {
            float s0 = __uint_as_float(__builtin_amdgcn_readlane(__float_as_uint(hA), kk));
            float s1 = __uint_as_float(__builtin_amdgcn_readlane(__float_as_uint(hB), kk));
            acc0 = fmaf(s0, Ucol[kk],      acc0);
            acc1 = fmaf(s1, Ucol[64 + kk], acc1);
        }
        float z = acc0 + acc1 + xpre;
        float g = (m == 2) ? tanhf(z) : hsig_f(z);
        gate_buf[tid] = g;

        // ---- fre gate: wave wv computes cols 2wv, 2wv+1 ----
        {
            float u0 = ufre_lds[lane * 17 + 2 * wv];
            float u1 = ufre_lds[(64 + lane) * 17 + 2 * wv];
            float u2 = ufre_lds[lane * 17 + 2 * wv + 1];
            float u3 = ufre_lds[(64 + lane) * 17 + 2 * wv + 1];
            float p0 = fmaf(hA, u0, hB * u1);
            float p1 = fmaf(hA, u2, hB * u3);
#pragma unroll
            for (int off = 1; off <= 32; off <<= 1) {
                p0 += __shfl_xor(p0, off, 64);
                p1 += __shfl_xor(p1, off, 64);
            }
            float ps = (lane & 1) ? p1 : p0;
            float fv = hsig_f(ps + xfrev);
            if (lane < 2) fre_buf[2 * wv + lane] = fv;
        }
        __syncthreads();   // gates + fre ready

        // ---- state update: thread owns (h=hh, f=f0..f0+3) ----
        {
            float iv = gate_buf[hh];
            float sv = gate_buf[128 + hh];
            float tc = gate_buf[256 + hh];
            float ov = gate_buf[384 + hh];
            float c  = iv * tc;
            float aacc;

            idx0 = (idx0 + f0 + 0) & 15;
            idx1 = (idx1 + f0 + 1) & 15;
            idx2 = (idx2 + f0 + 2) & 15;
            idx3 = (idx3 + f0 + 3) & 15;

            float fc;
            fc = sv * fre_buf[f0 + 0];
            Sre0 = fmaf(fc, Sre0, c * costab[idx0]);
            Sim0 = fmaf(fc, Sim0, c * sintab[idx0]);
            aacc = fmaf(Sre0, Sre0, Sim0 * Sim0) * ua4[0];

            fc = sv * fre_buf[f0 + 1];
            Sre1 = fmaf(fc, Sre1, c * costab[idx1]);
            Sim1 = fmaf(fc, Sim1, c * sintab[idx1]);
            aacc = fmaf(fmaf(Sre1, Sre1, Sim1 * Sim1), ua4[1], aacc);

            fc = sv * fre_buf[f0 + 2];
            Sre2 = fmaf(fc, Sre2, c * costab[idx2]);
            Sim2 = fmaf(fc, Sim2, c * sintab[idx2]);
            aacc = fmaf(fmaf(Sre2, Sre2, Sim2 * Sim2), ua4[2], aacc);

            fc = sv * fre_buf[f0 + 3];
            Sre3 = fmaf(fc, Sre3, c * costab[idx3]);
            Sim3 = fmaf(fc, Sim3, c * sintab[idx3]);
            aacc = fmaf(fmaf(Sre3, Sre3, Sim3 * Sim3), ua4[3], aacc);

            aacc += __shfl_xor(aacc, 1, 64);
            aacc += __shfl_xor(aacc, 2, 64);
            if ((tid & 3) == 0) {
                float a = tanhf(aacc + ba);
                h_buf[hh] = ov * a;
            }
        }
        __syncthreads();   // h ready
        hA = h_buf[lane];
        hB = h_buf[64 + lane];
        pr += 528;
    }

    // ---- output: out[b] = h @ W_sym + b_sym ----
    if (wv == 0) {
        float v = fmaf(hA, Wsym[lane], hB * Wsym[64 + lane]);
#pragma unroll
        for (int off = 1; off <= 32; off <<= 1) v += __shfl_xor(v, off, 64);
        if (lane == 0) out[b] = v + bsym[0];
    }
}

extern "C" void kernel_launch(void* const* d_in, const int* in_sizes, int n_in,
                              void* d_out, int out_size, void* d_ws, size_t ws_size,
                              hipStream_t stream) {
    const float* input = (const float*)d_in[0];
    const float* W_i   = (const float*)d_in[1];
    const float* U_i   = (const float*)d_in[2];
    // d_in[3] = b_i
    const float* b_i   = (const float*)d_in[3];
    const float* W_ste = (const float*)d_in[4];
    const float* U_ste = (const float*)d_in[5];
    const float* b_ste = (const float*)d_in[6];
    const float* W_fre = (const float*)d_in[7];
    const float* U_fre = (const float*)d_in[8];
    const float* b_fre = (const float*)d_in[9];
    const float* W_c   = (const float*)d_in[10];
    const float* U_c   = (const float*)d_in[11];
    const float* b_c   = (const float*)d_in[12];
    const float* W_o   = (const float*)d_in[13];
    const float* U_o   = (const float*)d_in[14];
    const float* b_o   = (const float*)d_in[15];
    const float* U_a   = (const float*)d_in[16];
    const float* b_a   = (const float*)d_in[17];
    const float* W_sym = (const float*)d_in[18];
    const float* b_sym = (const float*)d_in[19];

    float* P = (float*)d_ws;  // 32768 x 528 fp32 = 69.2 MB

    proj_gemm<<<dim3(512, 9), 256, 0, stream>>>(
        input, W_i, W_ste, W_c, W_o, W_fre,
        b_i, b_ste, b_c, b_o, b_fre, P);

    recur_kernel<<<256, 512, 0, stream>>>(
        P, U_i, U_ste, U_c, U_o, U_fre,
        U_a, b_a, W_sym, b_sym, (float*)d_out);
}

// Round 4
// 382.942 us; speedup vs baseline: 1.0576x; 1.0576x over previous
//
#include <hip/hip_runtime.h>
#include <hip/hip_bf16.h>

// SFM model: B=256, T=128, D=128, FREQ=16, HID=128
// Phase 1: P[(b*128+t)*528 + c] = x(b,t,:) @ [W_i|W_ste|W_c|W_o|W_fre] + bias
// Phase 2: sequential scan. 1024 thr/block, 1 batch/block. Each thread holds a
//          64-element half-column of one U matrix in VGPRs (spill-proof size),
//          h broadcast via readlane, split-K partials combined through LDS.

__device__ __forceinline__ float hsig_f(float z) {
    return fminf(fmaxf(z * (1.0f / 6.0f) + 0.5f, 0.0f), 1.0f);
}

// ---------------- Phase 1: projection GEMM ----------------
// grid = 256 (one batch each), block = 512. LDS: X tile 64KB + W tile 64KB.
__global__ __launch_bounds__(512) void proj_gemm(
    const float* __restrict__ input,
    const float* __restrict__ Wi, const float* __restrict__ Wste,
    const float* __restrict__ Wc, const float* __restrict__ Wo,
    const float* __restrict__ Wfre,
    const float* __restrict__ bi, const float* __restrict__ bste,
    const float* __restrict__ bc, const float* __restrict__ bo,
    const float* __restrict__ bfre,
    float* __restrict__ P)
{
    __shared__ __align__(16) float XT[128 * 128];  // [d][t] — linear copy of batch block
    __shared__ __align__(16) float WT[128 * 128];  // [d][cc]

    const int b   = blockIdx.x;
    const int tid = threadIdx.x;

    // Stage X: input[b*16384 + d*128 + t] is already [d][t] contiguous.
    const float* xb = input + (size_t)b * 16384;
#pragma unroll
    for (int i = 0; i < 8; i++) {
        int idx4 = (i * 512 + tid) * 4;
        *(float4*)(&XT[idx4]) = *(const float4*)(xb + idx4);
    }

    const int tx   = tid & 15;   // col group: cols {4tx..4tx+3} and {64+4tx..}
    const int ty   = tid >> 4;   // row group: rows ty*4..ty*4+3
    const int col0 = tx * 4;

    const float* Ws[5]    = {Wi, Wste, Wc, Wo, Wfre};
    const float* biases[5]= {bi, bste, bc, bo, bfre};

    for (int ct = 0; ct < 5; ct++) {
        const float* W = Ws[ct];
        if (ct < 4) {
#pragma unroll
            for (int i = 0; i < 8; i++) {
                int idx4 = (i * 512 + tid) * 4;
                *(float4*)(&WT[idx4]) = *(const float4*)(W + idx4);
            }
        } else {
            // Wfre: 128x16 -> WT[d*128 + cc] (cc<16)
            int idx4 = tid * 4;
            if (idx4 < 2048) {
                int d = idx4 >> 4, cc = idx4 & 15;
                *(float4*)(&WT[d * 128 + cc]) = *(const float4*)(W + idx4);
            }
        }
        __syncthreads();

        float acc[4][8] = {};
#pragma unroll 2
        for (int k = 0; k < 128; k++) {
            float4 xa = *(const float4*)(&XT[k * 128 + ty * 4]);
            float4 w0 = *(const float4*)(&WT[k * 128 + col0]);
            float4 w1 = *(const float4*)(&WT[k * 128 + 64 + col0]);
            const float xr[4] = {xa.x, xa.y, xa.z, xa.w};
            const float wc[8] = {w0.x, w0.y, w0.z, w0.w, w1.x, w1.y, w1.z, w1.w};
#pragma unroll
            for (int r = 0; r < 4; r++)
#pragma unroll
                for (int cc = 0; cc < 8; cc++)
                    acc[r][cc] = fmaf(xr[r], wc[cc], acc[r][cc]);
        }

        const int cbase = (ct < 4) ? ct * 128 : 512;
        const float* bias = biases[ct];
#pragma unroll
        for (int half = 0; half < 2; half++) {
            int colg = half * 64 + col0;
            bool valid = (ct < 4) || (colg < 16);
            if (valid) {
                float4 b4;
                b4.x = bias[colg + 0]; b4.y = bias[colg + 1];
                b4.z = bias[colg + 2]; b4.w = bias[colg + 3];
#pragma unroll
                for (int r = 0; r < 4; r++) {
                    int row = b * 128 + ty * 4 + r;
                    float4 o;
                    o.x = acc[r][half * 4 + 0] + b4.x;
                    o.y = acc[r][half * 4 + 1] + b4.y;
                    o.z = acc[r][half * 4 + 2] + b4.z;
                    o.w = acc[r][half * 4 + 3] + b4.w;
                    *(float4*)(&P[(size_t)row * 528 + cbase + colg]) = o;
                }
            }
        }
        __syncthreads();  // WT reused next ct
    }
}

// ---------------- Phase 2: sequential recurrence ----------------
// 1024 threads. tid -> half = tid>>9 (k-split), c = tid&511, m = c>>7, j = c&127.
// State ownership: hh = tid>>3 (0..127), fsel = tid&7 -> freqs {fsel, fsel+8}.
__global__ __launch_bounds__(1024) void recur_kernel(
    const float* __restrict__ P,
    const float* __restrict__ Ui, const float* __restrict__ Uste,
    const float* __restrict__ Uc, const float* __restrict__ Uo,
    const float* __restrict__ Ufre,
    const float* __restrict__ Ua, const float* __restrict__ ba_g,
    const float* __restrict__ Wsym, const float* __restrict__ bsym,
    float* __restrict__ out)
{
    __shared__ float ufre_t[16 * 132];   // [col][k] stride 132 (16B aligned rows)
    __shared__ float costab[16], sintab[16];
    __shared__ float gate_buf[512];      // [i|ste|c|o] x 128
    __shared__ float partial_buf[512];   // half-1 matvec partials
    __shared__ float fre_buf[16];
    __shared__ float h_buf[128];

    const int tid  = threadIdx.x;
    const int lane = tid & 63;
    const int half = tid >> 9;
    const int c    = tid & 511;
    const int m    = c >> 7;
    const int j    = c & 127;
    const int hh   = tid >> 3;     // 0..127
    const int fsel = tid & 7;      // freqs fsel, fsel+8
    const int b    = blockIdx.x;

    // one-time LDS init
    for (int e = tid; e < 2048; e += 1024) {
        int k = e >> 4, col = e & 15;
        ufre_t[col * 132 + k] = Ufre[e];
    }
    if (tid < 16) {
        float ang = 6.283185307179586f * (float)tid * (1.0f / 16.0f);
        costab[tid] = cosf(ang);
        sintab[tid] = sinf(ang);
    }
    if (tid < 128) h_buf[tid] = 0.0f;

    // 64-element half-column of U in registers (coalesced over j)
    const float* Uptr = (m == 0) ? Ui : (m == 1) ? Uste : (m == 2) ? Uc : Uo;
    float Ucol[64];
#pragma unroll
    for (int k = 0; k < 64; k++) Ucol[k] = Uptr[(half * 64 + k) * 128 + j];

    const float ua0 = Ua[fsel];
    const float ua1 = Ua[fsel + 8];
    const float ba  = ba_g[hh];

    float hA = 0.0f;               // h[half*64 + lane], wave-replicated
    float Sre0 = 0.f, Sim0 = 0.f, Sre1 = 0.f, Sim1 = 0.f;
    int idx0 = 0, idx1 = 0;

    __syncthreads();

    const float* pr = P + (size_t)b * 128 * 528;
    for (int t = 0; t < 128; t++) {
        // global prefetch (consumed after barrier 1 — latency hidden by matvec)
        const float xpre = (half == 0) ? pr[c] : pr[512 + (c >> 5)];

        // ---- matvec partial: acc = sum_{k in half} h[k] * U[k][j] ----
        float a0 = 0.f, a1 = 0.f;
#pragma unroll
        for (int kk = 0; kk < 64; kk += 2) {
            float s0 = __uint_as_float(__builtin_amdgcn_readlane(__float_as_uint(hA), kk));
            float s1 = __uint_as_float(__builtin_amdgcn_readlane(__float_as_uint(hA), kk + 1));
            a0 = fmaf(s0, Ucol[kk],     a0);
            a1 = fmaf(s1, Ucol[kk + 1], a1);
        }
        float acc = a0 + a1;

        if (half) partial_buf[c] = acc;
        __syncthreads();  // B1: partials visible

        if (half == 0) {
            float z = acc + partial_buf[c] + xpre;
            float g = (m == 2) ? tanhf(z) : hsig_f(z);
            gate_buf[c] = g;
        } else {
            // fre gate: col = c>>5, 32 threads per col, 4 k's each (h_buf still old h)
            const int col = c >> 5, kg = c & 31;
            float4 hv = *(const float4*)(&h_buf[kg * 4]);
            float4 uv = *(const float4*)(&ufre_t[col * 132 + kg * 4]);
            float p = fmaf(hv.x, uv.x, fmaf(hv.y, uv.y, fmaf(hv.z, uv.z, hv.w * uv.w)));
#pragma unroll
            for (int off = 1; off <= 16; off <<= 1) p += __shfl_xor(p, off, 64);
            if (kg == 0) fre_buf[col] = hsig_f(p + xpre);
        }
        __syncthreads();  // B2: gates + fre ready

        // ---- state update: thread owns (hh, freqs fsel & fsel+8) ----
        {
            float iv = gate_buf[hh];
            float sv = gate_buf[128 + hh];
            float tc = gate_buf[256 + hh];
            float ov = gate_buf[384 + hh];
            float cg = iv * tc;

            idx0 = (idx0 + fsel) & 15;
            idx1 = (idx1 + fsel + 8) & 15;

            float f0v = sv * fre_buf[fsel];
            float f1v = sv * fre_buf[fsel + 8];
            Sre0 = fmaf(f0v, Sre0, cg * costab[idx0]);
            Sim0 = fmaf(f0v, Sim0, cg * sintab[idx0]);
            Sre1 = fmaf(f1v, Sre1, cg * costab[idx1]);
            Sim1 = fmaf(f1v, Sim1, cg * sintab[idx1]);

            float aacc = fmaf(Sre0, Sre0, Sim0 * Sim0) * ua0;
            aacc = fmaf(fmaf(Sre1, Sre1, Sim1 * Sim1), ua1, aacc);
            aacc += __shfl_xor(aacc, 1, 64);
            aacc += __shfl_xor(aacc, 2, 64);
            aacc += __shfl_xor(aacc, 4, 64);
            if (fsel == 0) {
                float a = tanhf(aacc + ba);
                h_buf[hh] = ov * a;
            }
        }
        __syncthreads();  // B3: h ready
        hA = h_buf[half * 64 + lane];
        pr += 528;
    }

    // ---- output: out[b] = h @ W_sym + b_sym ----
    if (tid < 64) {
        float v = fmaf(h_buf[lane], Wsym[lane], h_buf[64 + lane] * Wsym[64 + lane]);
#pragma unroll
        for (int off = 1; off <= 32; off <<= 1) v += __shfl_xor(v, off, 64);
        if (lane == 0) out[b] = v + bsym[0];
    }
}

extern "C" void kernel_launch(void* const* d_in, const int* in_sizes, int n_in,
                              void* d_out, int out_size, void* d_ws, size_t ws_size,
                              hipStream_t stream) {
    const float* input = (const float*)d_in[0];
    const float* W_i   = (const float*)d_in[1];
    const float* U_i   = (const float*)d_in[2];
    const float* b_i   = (const float*)d_in[3];
    const float* W_ste = (const float*)d_in[4];
    const float* U_ste = (const float*)d_in[5];
    const float* b_ste = (const float*)d_in[6];
    const float* W_fre = (const float*)d_in[7];
    const float* U_fre = (const float*)d_in[8];
    const float* b_fre = (const float*)d_in[9];
    const float* W_c   = (const float*)d_in[10];
    const float* U_c   = (const float*)d_in[11];
    const float* b_c   = (const float*)d_in[12];
    const float* W_o   = (const float*)d_in[13];
    const float* U_o   = (const float*)d_in[14];
    const float* b_o   = (const float*)d_in[15];
    const float* U_a   = (const float*)d_in[16];
    const float* b_a   = (const float*)d_in[17];
    const float* W_sym = (const float*)d_in[18];
    const float* b_sym = (const float*)d_in[19];

    float* P = (float*)d_ws;  // 32768 x 528 fp32 = 69.2 MB

    proj_gemm<<<256, 512, 0, stream>>>(
        input, W_i, W_ste, W_c, W_o, W_fre,
        b_i, b_ste, b_c, b_o, b_fre, P);

    recur_kernel<<<256, 1024, 0, stream>>>(
        P, U_i, U_ste, U_c, U_o, U_fre,
        U_a, b_a, W_sym, b_sym, (float*)d_out);
}